// Round 7
// baseline (331.849 us; speedup 1.0000x reference)
//
#include <hip/hip_runtime.h>
#include <hip/hip_cooperative_groups.h>
#include <stdint.h>

// AttentionHead: B=4, S=2048, E=1024, H=64, causal, scale = E^-0.5 = 1/32.
// R7: cooperative fused kernel, 256 blocks (co-resident even at 1 block/CU)
// x 512 threads, 2 tiles/block/phase paired (x, 511-x) for load balance.
// Checked launch + fallback to the verified R5 three-kernel pipeline.

namespace cg = cooperative_groups;

typedef __bf16 bf16_t;
typedef __bf16 bf16x8 __attribute__((ext_vector_type(8)));
typedef __bf16 bf16x4 __attribute__((ext_vector_type(4)));
typedef float floatx4 __attribute__((ext_vector_type(4)));

#define MFMA16(a, b, c) __builtin_amdgcn_mfma_f32_16x16x32_bf16((a), (b), (c), 0, 0, 0)

// log2(e) / sqrt(1024): folded into Wq so scores come out in exp2 domain.
static constexpr float kQScale = 0.04508422002778f;
#define NEG_BIG (-3.0e38f)

__device__ inline bf16x4 cvt4(float4 f) {
  bf16x4 v;
  v[0] = (bf16_t)f.x; v[1] = (bf16_t)f.y; v[2] = (bf16_t)f.z; v[3] = (bf16_t)f.w;
  return v;
}

// ===================== fused cooperative kernel ============================
// LDS plan (byte offsets), phases separated by barriers/grid.sync:
//   P1a: As bf16[16][1032]       @0     (33024 B)
//   P1b: red float[4][12][64]    @0     (12288 B)  Cs bf16[16][136] @12288
//   P2 : Ol float[8][16][65]     @0     (33280 B)  Ll float[8][16]  @33280
#define SMEM_BYTES 33792

__global__ __launch_bounds__(512, 4) void fused_kernel(
    const float* __restrict__ tok, const float* __restrict__ Wq,
    const float* __restrict__ Wk, const float* __restrict__ Wv,
    bf16_t* __restrict__ Bp, bf16_t* __restrict__ qw,
    bf16_t* __restrict__ kw, bf16_t* __restrict__ vw,
    float* __restrict__ out) {
  __shared__ __align__(16) char smem[SMEM_BYTES];
  cg::grid_group gridg = cg::this_grid();

  const int tx = threadIdx.x;
  const int wave = tx >> 6, lane = tx & 63;
  const int lanelo = lane & 15, quad = lane >> 4;

  // =================== P0: W -> Bp in MFMA B-fragment order ===============
#pragma unroll
  for (int it = 0; it < 2; it++) {
    const int tid = it * 131072 + blockIdx.x * 512 + tx;
    if (tid < 196608) {
      const int j = tid & 7;
      const int ln = (tid >> 3) & 63;
      const int ks = (tid >> 9) & 31;
      const int nt = tid >> 14;  // 0..11
      const int m = nt >> 2, n4 = nt & 3;
      const int h = n4 * 16 + (ln & 15);
      const int e = ks * 32 + ((ln >> 4) << 3) + j;
      const float* W = (m == 0) ? Wq : ((m == 1) ? Wk : Wv);
      float v = W[e * 64 + h];
      if (m == 0) v *= kQScale;
      Bp[tid] = (bf16_t)v;
    }
  }
  __threadfence();
  gridg.sync();
  __threadfence();

  // =================== P1: projection GEMM (2 tiles/block) ================
  for (int it = 0; it < 2; it++) {
    __syncthreads();
    const int tile = (it == 0) ? blockIdx.x : 511 - blockIdx.x;
    bf16_t* As = (bf16_t*)smem;  // [16][1032]
    const int grow = tile * 16;
    const int b = grow >> 11;
    const int t = (grow & 2047) >> 4;

#pragma unroll
    for (int i = 0; i < 8; i++) {
      const int f = i * 512 + tx;  // 4096 float4 total
      const int row = f >> 8, c4 = f & 255;
      const float4 v = *(const float4*)(tok + (grow + row) * 1024 + c4 * 4);
      *(bf16x4*)&As[row * 1032 + c4 * 4] = cvt4(v);
    }
    __syncthreads();

    const int ng = wave & 3, kh = wave >> 2;
    floatx4 acc[3];
#pragma unroll
    for (int i = 0; i < 3; i++) acc[i] = (floatx4){0.f, 0.f, 0.f, 0.f};
    const bf16_t* bp[3];
#pragma unroll
    for (int j = 0; j < 3; j++)
      bp[j] = Bp + (ng * 3 + j) * 16384 + lane * 8;
    const bf16_t* ab = &As[lanelo * 1032 + quad * 8];

#pragma unroll
    for (int ks = 0; ks < 16; ks++) {
      const int kk = kh * 16 + ks;
      const bf16x8 af = *(const bf16x8*)(ab + kk * 32);
#pragma unroll
      for (int j = 0; j < 3; j++)
        acc[j] = MFMA16(af, *(const bf16x8*)(bp[j] + kk * 512), acc[j]);
    }
    __syncthreads();  // all waves done with As

    float* red = (float*)smem;             // [4][12][64]
    bf16_t* Cs = (bf16_t*)(smem + 12288);  // [16][136]
    if (kh == 1) {
#pragma unroll
      for (int j = 0; j < 3; j++)
#pragma unroll
        for (int r = 0; r < 4; r++)
          red[(ng * 12 + j * 4 + r) * 64 + lane] = acc[j][r];
    }
    __syncthreads();
    if (kh == 0) {
#pragma unroll
      for (int j = 0; j < 3; j++) {
        const int nt = ng * 3 + j;
        const int n4 = nt & 3, mtx = nt >> 2;
#pragma unroll
        for (int r = 0; r < 4; r++)
          acc[j][r] += red[(ng * 12 + j * 4 + r) * 64 + lane];
        if (mtx < 2) {
#pragma unroll
          for (int r = 0; r < 4; r++)
            Cs[(quad * 4 + r) * 136 + mtx * 64 + n4 * 16 + lanelo] = (bf16_t)acc[j][r];
        } else {
          bf16x4 pk;
#pragma unroll
          for (int r = 0; r < 4; r++) pk[r] = (bf16_t)acc[j][r];
          const int base = (((b * 32 + (t >> 2)) * 2 + ((t >> 1) & 1)) * 4 + n4) * 512
                         + (quad * 16 + lanelo) * 8 + (t & 1) * 4;
          *(bf16x4*)(vw + base) = pk;
        }
      }
    }
    __syncthreads();
    if (tx < 256) {
      const int mtx = tx >> 7, idx = tx & 127;
      const int ds = idx >> 6, lp = idx & 63;
      const int qr = lp & 15, h8 = ds * 32 + ((lp >> 4) << 3);
      const bf16x8 val = *(const bf16x8*)&Cs[qr * 136 + mtx * 64 + h8];
      bf16_t* dst = mtx ? kw : qw;
      *(bf16x8*)(dst + (b * 128 + t) * 1024 + idx * 8) = val;
    }
  }
  __threadfence();
  gridg.sync();
  __threadfence();

  // =================== P2: flash attention (2 tiles/block) ================
  for (int it = 0; it < 2; it++) {
    __syncthreads();
    const int tile = (it == 0) ? blockIdx.x : 511 - blockIdx.x;
    float* Ol = (float*)smem;            // [8][16][65]
    float* Ll = (float*)(smem + 33280);  // [8][16]

    const int b = tile & 3;
    const int t = 127 - (tile >> 2);
    const int qbase = t * 16;
    const int grow = b * 2048 + qbase;

    const bf16_t* qp = qw + ((b * 128 + t) * 128 + lane) * 8;
    const bf16x8 qa0 = *(const bf16x8*)qp;
    const bf16x8 qa1 = *(const bf16x8*)(qp + 512);

    bf16x8 ones;
#pragma unroll
    for (int j = 0; j < 8; j++) ones[j] = (bf16_t)1.0f;

    floatx4 O[4];  // O^T: [dt] reg r -> row d=dt*16+quad*4+r, col q=lanelo
#pragma unroll
    for (int i = 0; i < 4; i++) O[i] = (floatx4){0.f, 0.f, 0.f, 0.f};
    floatx4 lacc = (floatx4){0.f, 0.f, 0.f, 0.f};

    const int nch = (qbase + 16 + 63) >> 6;
    const bf16_t* kb = kw + b * 131072 + lane * 8;
    const bf16_t* vb = vw + b * 131072 + lane * 8;

    for (int c = wave; c < nch; c += 8) {
      const int cb = c * 64;
      floatx4 s[4];
      const floatx4 z = (floatx4){0.f, 0.f, 0.f, 0.f};
#pragma unroll
      for (int sub = 0; sub < 4; sub++) {
        const bf16_t* kp = kb + (c * 4 + sub) * 1024;
        s[sub] = MFMA16(*(const bf16x8*)kp, qa0, z);
        s[sub] = MFMA16(*(const bf16x8*)(kp + 512), qa1, s[sub]);
      }

      if (cb + 63 > qbase) {
#pragma unroll
        for (int sub = 0; sub < 4; sub++) {
          const int keyr = cb + sub * 16 + quad * 4;
#pragma unroll
          for (int r = 0; r < 4; r++)
            if (keyr + r > qbase + lanelo) s[sub][r] = NEG_BIG;
        }
      }

      bf16x8 pa0, pa1;
#pragma unroll
      for (int r = 0; r < 4; r++) {
        pa0[r]     = (bf16_t)__builtin_amdgcn_exp2f(s[0][r]);
        pa0[4 + r] = (bf16_t)__builtin_amdgcn_exp2f(s[1][r]);
        pa1[r]     = (bf16_t)__builtin_amdgcn_exp2f(s[2][r]);
        pa1[4 + r] = (bf16_t)__builtin_amdgcn_exp2f(s[3][r]);
      }

      const bf16_t* vp = vb + c * 4096;
#pragma unroll
      for (int dt = 0; dt < 4; dt++) {
        O[dt] = MFMA16(*(const bf16x8*)(vp + dt * 512), pa0, O[dt]);
        O[dt] = MFMA16(*(const bf16x8*)(vp + 2048 + dt * 512), pa1, O[dt]);
      }
      lacc = MFMA16(ones, pa0, lacc);
      lacc = MFMA16(ones, pa1, lacc);
    }

    // cross-wave merge: plain sums
#pragma unroll
    for (int dt = 0; dt < 4; dt++)
#pragma unroll
      for (int r = 0; r < 4; r++)
        Ol[(wave * 16 + lanelo) * 65 + dt * 16 + quad * 4 + r] = O[dt][r];
    if (quad == 0) Ll[wave * 16 + lanelo] = lacc[0];
    __syncthreads();

#pragma unroll
    for (int o = tx; o < 1024; o += 512) {
      const int row = o >> 6, d = o & 63;
      float L = 0.f, acc = 0.f;
#pragma unroll
      for (int w = 0; w < 8; w++) {
        L += Ll[w * 16 + row];
        acc += Ol[(w * 16 + row) * 65 + d];
      }
      out[(grow + row) * 64 + d] = acc / L;
    }
  }
}

// ===================== fallback: verified R5 three-kernel pipeline =========
__global__ __launch_bounds__(256) void wt_kernel(const float* __restrict__ Wq,
                                                 const float* __restrict__ Wk,
                                                 const float* __restrict__ Wv,
                                                 bf16_t* __restrict__ Bp) {
  const int tid = blockIdx.x * 256 + threadIdx.x;
  const int j = tid & 7;
  const int lane = (tid >> 3) & 63;
  const int ks = (tid >> 9) & 31;
  const int nt = tid >> 14;
  const int m = nt >> 2, n4 = nt & 3;
  const int h = n4 * 16 + (lane & 15);
  const int e = ks * 32 + ((lane >> 4) << 3) + j;
  const float* W = (m == 0) ? Wq : ((m == 1) ? Wk : Wv);
  float v = W[e * 64 + h];
  if (m == 0) v *= kQScale;
  Bp[tid] = (bf16_t)v;
}

__global__ __launch_bounds__(256) void proj_kernel(const float* __restrict__ tok,
                                                   const bf16_t* __restrict__ Bp,
                                                   bf16_t* __restrict__ qw,
                                                   bf16_t* __restrict__ kw,
                                                   bf16_t* __restrict__ vw) {
  __shared__ bf16_t As[2][16][264];
  const int tx = threadIdx.x;
  const int wave = tx >> 6, lane = tx & 63;
  const int lanelo = lane & 15, quad = lane >> 4;
  const int grow = blockIdx.x * 16;
  const int b = grow >> 11;
  const int t = (grow & 2047) >> 4;

  const float* tokbase = tok + (grow + wave) * 1024 + lane * 4;

  floatx4 acc[3];
#pragma unroll
  for (int i = 0; i < 3; i++) acc[i] = (floatx4){0.f, 0.f, 0.f, 0.f};

  const bf16_t* bp[3];
#pragma unroll
  for (int j = 0; j < 3; j++)
    bp[j] = Bp + (wave * 3 + j) * 16384 + lane * 8;

  float4 tb[4];
#pragma unroll
  for (int r = 0; r < 4; r++) tb[r] = *(const float4*)(tokbase + r * 4096);
#pragma unroll
  for (int r = 0; r < 4; r++)
    *(bf16x4*)&As[0][r * 4 + wave][lane * 4] = cvt4(tb[r]);
  __syncthreads();

  for (int c = 0; c < 4; c++) {
    if (c < 3) {
#pragma unroll
      for (int r = 0; r < 4; r++)
        tb[r] = *(const float4*)(tokbase + r * 4096 + (c + 1) * 256);
    }
    const bf16_t* ab = &As[c & 1][lanelo][quad * 8];
#pragma unroll
    for (int ks = 0; ks < 8; ks++) {
      const bf16x8 af = *(const bf16x8*)(ab + ks * 32);
#pragma unroll
      for (int j = 0; j < 3; j++) {
        const bf16x8 bfr = *(const bf16x8*)(bp[j] + (c * 8 + ks) * 512);
        acc[j] = MFMA16(af, bfr, acc[j]);
      }
    }
    if (c < 3) {
#pragma unroll
      for (int r = 0; r < 4; r++)
        *(bf16x4*)&As[(c + 1) & 1][r * 4 + wave][lane * 4] = cvt4(tb[r]);
    }
    __syncthreads();
  }

  bf16_t* Cs = (bf16_t*)As;
#pragma unroll
  for (int j = 0; j < 3; j++) {
    const int nt = wave * 3 + j;
    const int n4 = nt & 3, mtx = nt >> 2;
    if (mtx < 2) {
#pragma unroll
      for (int r = 0; r < 4; r++)
        Cs[(quad * 4 + r) * 136 + mtx * 64 + n4 * 16 + lanelo] = (bf16_t)acc[j][r];
    } else {
      bf16x4 pk;
#pragma unroll
      for (int r = 0; r < 4; r++) pk[r] = (bf16_t)acc[j][r];
      const int base = (((b * 32 + (t >> 2)) * 2 + ((t >> 1) & 1)) * 4 + n4) * 512
                     + (quad * 16 + lanelo) * 8 + (t & 1) * 4;
      *(bf16x4*)(vw + base) = pk;
    }
  }
  __syncthreads();
  {
    const int mtx = tx >> 7, idx = tx & 127;
    const int ds = idx >> 6, lp = idx & 63;
    const int qr = lp & 15, h8 = ds * 32 + ((lp >> 4) << 3);
    const bf16x8 val = *(const bf16x8*)&Cs[qr * 136 + mtx * 64 + h8];
    bf16_t* dst = mtx ? kw : qw;
    *(bf16x8*)(dst + (b * 128 + t) * 1024 + idx * 8) = val;
  }
}

__global__ __launch_bounds__(512, 4) void attn_kernel(const bf16_t* __restrict__ qw,
                                                      const bf16_t* __restrict__ kw,
                                                      const bf16_t* __restrict__ vw,
                                                      float* __restrict__ out) {
  __shared__ float Ol[8][16][65];
  __shared__ float Ll[8][16];

  const int wave = threadIdx.x >> 6;
  const int lane = threadIdx.x & 63;
  const int lanelo = lane & 15;
  const int quad = lane >> 4;

  const int b = blockIdx.x & 3;
  const int t = 127 - (blockIdx.x >> 2);
  const int qbase = t * 16;
  const int grow = b * 2048 + qbase;

  const bf16_t* qp = qw + ((b * 128 + t) * 128 + lane) * 8;
  const bf16x8 qa0 = *(const bf16x8*)qp;
  const bf16x8 qa1 = *(const bf16x8*)(qp + 512);

  bf16x8 ones;
#pragma unroll
  for (int j = 0; j < 8; j++) ones[j] = (bf16_t)1.0f;

  floatx4 O[4];
#pragma unroll
  for (int i = 0; i < 4; i++) O[i] = (floatx4){0.f, 0.f, 0.f, 0.f};
  floatx4 lacc = (floatx4){0.f, 0.f, 0.f, 0.f};

  const int nch = (qbase + 16 + 63) >> 6;
  const bf16_t* kb = kw + b * 131072 + lane * 8;
  const bf16_t* vb = vw + b * 131072 + lane * 8;

  for (int c = wave; c < nch; c += 8) {
    const int cb = c * 64;
    floatx4 s[4];
    const floatx4 z = (floatx4){0.f, 0.f, 0.f, 0.f};
#pragma unroll
    for (int sub = 0; sub < 4; sub++) {
      const bf16_t* kp = kb + (c * 4 + sub) * 1024;
      s[sub] = MFMA16(*(const bf16x8*)kp, qa0, z);
      s[sub] = MFMA16(*(const bf16x8*)(kp + 512), qa1, s[sub]);
    }

    if (cb + 63 > qbase) {
#pragma unroll
      for (int sub = 0; sub < 4; sub++) {
        const int keyr = cb + sub * 16 + quad * 4;
#pragma unroll
        for (int r = 0; r < 4; r++)
          if (keyr + r > qbase + lanelo) s[sub][r] = NEG_BIG;
      }
    }

    bf16x8 pa0, pa1;
#pragma unroll
    for (int r = 0; r < 4; r++) {
      pa0[r]     = (bf16_t)__builtin_amdgcn_exp2f(s[0][r]);
      pa0[4 + r] = (bf16_t)__builtin_amdgcn_exp2f(s[1][r]);
      pa1[r]     = (bf16_t)__builtin_amdgcn_exp2f(s[2][r]);
      pa1[4 + r] = (bf16_t)__builtin_amdgcn_exp2f(s[3][r]);
    }

    const bf16_t* vp = vb + c * 4096;
#pragma unroll
    for (int dt = 0; dt < 4; dt++) {
      O[dt] = MFMA16(*(const bf16x8*)(vp + dt * 512), pa0, O[dt]);
      O[dt] = MFMA16(*(const bf16x8*)(vp + 2048 + dt * 512), pa1, O[dt]);
    }
    lacc = MFMA16(ones, pa0, lacc);
    lacc = MFMA16(ones, pa1, lacc);
  }

#pragma unroll
  for (int dt = 0; dt < 4; dt++)
#pragma unroll
    for (int r = 0; r < 4; r++)
      Ol[wave][lanelo][dt * 16 + quad * 4 + r] = O[dt][r];
  if (quad == 0) Ll[wave][lanelo] = lacc[0];
  __syncthreads();

#pragma unroll
  for (int o = threadIdx.x; o < 1024; o += 512) {
    const int row = o >> 6, d = o & 63;
    float L = 0.f, acc = 0.f;
#pragma unroll
    for (int w = 0; w < 8; w++) {
      L += Ll[w][row];
      acc += Ol[w][row][d];
    }
    out[(grow + row) * 64 + d] = acc / L;
  }
}

// ---------------- launch ---------------------------------------------------
extern "C" void kernel_launch(void* const* d_in, const int* in_sizes, int n_in,
                              void* d_out, int out_size, void* d_ws, size_t ws_size,
                              hipStream_t stream) {
  const float* tokens = (const float*)d_in[0];
  const float* Wq = (const float*)d_in[1];
  const float* Wk = (const float*)d_in[2];
  const float* Wv = (const float*)d_in[3];
  float* out = (float*)d_out;

  char* ws = (char*)d_ws;
  // layout: Bp 384KB | q 1MB | k 1MB | v 1MB  (~3.4 MB total)
  if (ws_size < 3538944) return;
  bf16_t* Bp = (bf16_t*)ws;
  bf16_t* qw = (bf16_t*)(ws + 393216);
  bf16_t* kw = (bf16_t*)(ws + 393216 + 1048576);
  bf16_t* vw = (bf16_t*)(ws + 393216 + 2097152);

  void* args[] = {(void*)&tokens, (void*)&Wq, (void*)&Wk, (void*)&Wv,
                  (void*)&Bp, (void*)&qw, (void*)&kw, (void*)&vw, (void*)&out};
  hipError_t err = hipLaunchCooperativeKernel((const void*)fused_kernel,
                                              dim3(256), dim3(512), args, 0,
                                              stream);
  if (err != hipSuccess) {
    // deterministic fallback: verified R5 three-kernel pipeline
    hipLaunchKernelGGL(wt_kernel, dim3(768), dim3(256), 0, stream, Wq, Wk, Wv, Bp);
    hipLaunchKernelGGL(proj_kernel, dim3(512), dim3(256), 0, stream, tokens, Bp, qw, kw, vw);
    hipLaunchKernelGGL(attn_kernel, dim3(512), dim3(512), 0, stream, qw, kw, vw, out);
  }
}

// Round 8
// 101.355 us; speedup vs baseline: 3.2741x; 3.2741x over previous
//
#include <hip/hip_runtime.h>
#include <stdint.h>

// AttentionHead: B=4, S=2048, E=1024, H=64, causal, scale = E^-0.5 = 1/32.
// R8: back to 3-kernel pipeline (cooperative grid.sync measured ~100us/sync
// on this harness -> abandoned). proj: 32-row M-tiles (256 blk x 512 thr,
// 4 n-groups x 2 row-halves, full K per wave) halves Bp L2 traffic 196->98MB.
// wt + attn identical to verified R5.

typedef __bf16 bf16_t;
typedef __bf16 bf16x8 __attribute__((ext_vector_type(8)));
typedef __bf16 bf16x4 __attribute__((ext_vector_type(4)));
typedef float floatx4 __attribute__((ext_vector_type(4)));

#define MFMA16(a, b, c) __builtin_amdgcn_mfma_f32_16x16x32_bf16((a), (b), (c), 0, 0, 0)

// log2(e) / sqrt(1024): folded into Wq so scores come out in exp2 domain.
static constexpr float kQScale = 0.04508422002778f;
#define NEG_BIG (-3.0e38f)

__device__ inline bf16x4 cvt4(float4 f) {
  bf16x4 v;
  v[0] = (bf16_t)f.x; v[1] = (bf16_t)f.y; v[2] = (bf16_t)f.z; v[3] = (bf16_t)f.w;
  return v;
}

// ---------------- kernel 0: W -> Bp in MFMA B-fragment order ---------------
__global__ __launch_bounds__(256) void wt_kernel(const float* __restrict__ Wq,
                                                 const float* __restrict__ Wk,
                                                 const float* __restrict__ Wv,
                                                 bf16_t* __restrict__ Bp) {
  const int tid = blockIdx.x * 256 + threadIdx.x;
  const int j = tid & 7;
  const int lane = (tid >> 3) & 63;
  const int ks = (tid >> 9) & 31;
  const int nt = tid >> 14;
  const int m = nt >> 2, n4 = nt & 3;
  const int h = n4 * 16 + (lane & 15);
  const int e = ks * 32 + ((lane >> 4) << 3) + j;
  const float* W = (m == 0) ? Wq : ((m == 1) ? Wk : Wv);
  float v = W[e * 64 + h];
  if (m == 0) v *= kQScale;
  Bp[tid] = (bf16_t)v;
}

// ---------------- kernel 1: projection GEMM (32-row tiles) -----------------
// grid 256, block 512 = 8 waves: ng = wave&3 (3 n-tiles each), rh = wave>>2
// (16-row half). Full K per wave -> no reduction. Tokens staged fp32->bf16
// through double-buffered LDS (4 chunks of 256 cols). Bp read once per block
// for 32 rows (was per 16) -> half the L2 traffic.
__global__ __launch_bounds__(512) void proj_kernel(const float* __restrict__ tok,
                                                   const bf16_t* __restrict__ Bp,
                                                   bf16_t* __restrict__ qw,
                                                   bf16_t* __restrict__ kw,
                                                   bf16_t* __restrict__ vw) {
  __shared__ bf16_t As[2][32][264];  // 33792 B; reused as Cs in epilogue
  const int tx = threadIdx.x;
  const int wave = tx >> 6, lane = tx & 63;
  const int lanelo = lane & 15, quad = lane >> 4;
  const int ng = wave & 3, rh = wave >> 2;
  const int grow = blockIdx.x * 32;
  const int b = grow >> 11;
  const int t16 = ((grow & 2047) >> 4) + rh;  // this wave's 16-row tile id

  // staging: thread does 4 float4 per chunk; f = p*512+tx -> row f>>6, c4 f&63
  const int srow = tx >> 6;   // base row within chunk for p=0 (adds p*8)
  const int sc4 = tx & 63;
  const float* tokbase = tok + (grow + srow) * 1024 + sc4 * 4;

  floatx4 acc[3];
#pragma unroll
  for (int i = 0; i < 3; i++) acc[i] = (floatx4){0.f, 0.f, 0.f, 0.f};

  const bf16_t* bp[3];
#pragma unroll
  for (int j = 0; j < 3; j++)
    bp[j] = Bp + (ng * 3 + j) * 16384 + lane * 8;

  // prologue: stage chunk 0
  float4 tb[4];
#pragma unroll
  for (int p = 0; p < 4; p++) tb[p] = *(const float4*)(tokbase + p * 8 * 1024);
#pragma unroll
  for (int p = 0; p < 4; p++)
    *(bf16x4*)&As[0][srow + p * 8][sc4 * 4] = cvt4(tb[p]);
  __syncthreads();

  for (int c = 0; c < 4; c++) {
    if (c < 3) {
#pragma unroll
      for (int p = 0; p < 4; p++)
        tb[p] = *(const float4*)(tokbase + p * 8 * 1024 + (c + 1) * 256);
    }
    const bf16_t* ab = &As[c & 1][rh * 16 + lanelo][quad * 8];
#pragma unroll
    for (int ks = 0; ks < 8; ks++) {
      const bf16x8 af = *(const bf16x8*)(ab + ks * 32);
#pragma unroll
      for (int j = 0; j < 3; j++) {
        const bf16x8 bfr = *(const bf16x8*)(bp[j] + (c * 8 + ks) * 512);
        acc[j] = MFMA16(af, bfr, acc[j]);
      }
    }
    if (c < 3) {
#pragma unroll
      for (int p = 0; p < 4; p++)
        *(bf16x4*)&As[(c + 1) & 1][srow + p * 8][sc4 * 4] = cvt4(tb[p]);
    }
    __syncthreads();
  }

  // ---- epilogue ----
  // v: direct b64 store in kappa fragment order. q/k: restage via Cs[2][16][136].
  bf16_t* Cs = (bf16_t*)As;
#pragma unroll
  for (int j = 0; j < 3; j++) {
    const int nt = ng * 3 + j;
    const int n4 = nt & 3, mtx = nt >> 2;
    if (mtx < 2) {
#pragma unroll
      for (int r = 0; r < 4; r++)
        Cs[(rh * 16 + quad * 4 + r) * 136 + mtx * 64 + n4 * 16 + lanelo] =
            (bf16_t)acc[j][r];
    } else {
      bf16x4 pk;
#pragma unroll
      for (int r = 0; r < 4; r++) pk[r] = (bf16_t)acc[j][r];
      const int base = (((b * 32 + (t16 >> 2)) * 2 + ((t16 >> 1) & 1)) * 4 + n4) * 512
                     + (quad * 16 + lanelo) * 8 + (t16 & 1) * 4;
      *(bf16x4*)(vw + base) = pk;
    }
  }
  __syncthreads();
  {
    const int rh2 = tx >> 8;         // 0..1: which 16-row sub-tile
    const int mtx = (tx >> 7) & 1;   // 0=q, 1=k
    const int idx = tx & 127;
    const int ds = idx >> 6, lp = idx & 63;
    const int qr = lp & 15, h8 = ds * 32 + ((lp >> 4) << 3);
    const bf16x8 val = *(const bf16x8*)&Cs[(rh2 * 16 + qr) * 136 + mtx * 64 + h8];
    bf16_t* dst = mtx ? kw : qw;
    const int t2 = ((grow & 2047) >> 4) + rh2;
    *(bf16x8*)(dst + (b * 128 + t2) * 1024 + idx * 8) = val;
  }
}

// ---------------- kernel 2: flash attention (R5, verified) -----------------
__global__ __launch_bounds__(512, 4) void attn_kernel(const bf16_t* __restrict__ qw,
                                                      const bf16_t* __restrict__ kw,
                                                      const bf16_t* __restrict__ vw,
                                                      float* __restrict__ out) {
  __shared__ float Ol[8][16][65];
  __shared__ float Ll[8][16];

  const int wave = threadIdx.x >> 6;
  const int lane = threadIdx.x & 63;
  const int lanelo = lane & 15;
  const int quad = lane >> 4;

  const int b = blockIdx.x & 3;
  const int t = 127 - (blockIdx.x >> 2);
  const int qbase = t * 16;
  const int grow = b * 2048 + qbase;

  const bf16_t* qp = qw + ((b * 128 + t) * 128 + lane) * 8;
  const bf16x8 qa0 = *(const bf16x8*)qp;
  const bf16x8 qa1 = *(const bf16x8*)(qp + 512);

  bf16x8 ones;
#pragma unroll
  for (int j = 0; j < 8; j++) ones[j] = (bf16_t)1.0f;

  floatx4 O[4];
#pragma unroll
  for (int i = 0; i < 4; i++) O[i] = (floatx4){0.f, 0.f, 0.f, 0.f};
  floatx4 lacc = (floatx4){0.f, 0.f, 0.f, 0.f};

  const int nch = (qbase + 16 + 63) >> 6;
  const bf16_t* kb = kw + b * 131072 + lane * 8;
  const bf16_t* vb = vw + b * 131072 + lane * 8;

  for (int c = wave; c < nch; c += 8) {
    const int cb = c * 64;
    floatx4 s[4];
    const floatx4 z = (floatx4){0.f, 0.f, 0.f, 0.f};
#pragma unroll
    for (int sub = 0; sub < 4; sub++) {
      const bf16_t* kp = kb + (c * 4 + sub) * 1024;
      s[sub] = MFMA16(*(const bf16x8*)kp, qa0, z);
      s[sub] = MFMA16(*(const bf16x8*)(kp + 512), qa1, s[sub]);
    }

    if (cb + 63 > qbase) {
#pragma unroll
      for (int sub = 0; sub < 4; sub++) {
        const int keyr = cb + sub * 16 + quad * 4;
#pragma unroll
        for (int r = 0; r < 4; r++)
          if (keyr + r > qbase + lanelo) s[sub][r] = NEG_BIG;
      }
    }

    bf16x8 pa0, pa1;
#pragma unroll
    for (int r = 0; r < 4; r++) {
      pa0[r]     = (bf16_t)__builtin_amdgcn_exp2f(s[0][r]);
      pa0[4 + r] = (bf16_t)__builtin_amdgcn_exp2f(s[1][r]);
      pa1[r]     = (bf16_t)__builtin_amdgcn_exp2f(s[2][r]);
      pa1[4 + r] = (bf16_t)__builtin_amdgcn_exp2f(s[3][r]);
    }

    const bf16_t* vp = vb + c * 4096;
#pragma unroll
    for (int dt = 0; dt < 4; dt++) {
      O[dt] = MFMA16(*(const bf16x8*)(vp + dt * 512), pa0, O[dt]);
      O[dt] = MFMA16(*(const bf16x8*)(vp + 2048 + dt * 512), pa1, O[dt]);
    }
    lacc = MFMA16(ones, pa0, lacc);
    lacc = MFMA16(ones, pa1, lacc);
  }

#pragma unroll
  for (int dt = 0; dt < 4; dt++)
#pragma unroll
    for (int r = 0; r < 4; r++)
      Ol[wave][lanelo][dt * 16 + quad * 4 + r] = O[dt][r];
  if (quad == 0) Ll[wave][lanelo] = lacc[0];
  __syncthreads();

#pragma unroll
  for (int o = threadIdx.x; o < 1024; o += 512) {
    const int row = o >> 6, d = o & 63;
    float L = 0.f, acc = 0.f;
#pragma unroll
    for (int w = 0; w < 8; w++) {
      L += Ll[w][row];
      acc += Ol[w][row][d];
    }
    out[(grow + row) * 64 + d] = acc / L;
  }
}

// ---------------- launch ---------------------------------------------------
extern "C" void kernel_launch(void* const* d_in, const int* in_sizes, int n_in,
                              void* d_out, int out_size, void* d_ws, size_t ws_size,
                              hipStream_t stream) {
  const float* tokens = (const float*)d_in[0];
  const float* Wq = (const float*)d_in[1];
  const float* Wk = (const float*)d_in[2];
  const float* Wv = (const float*)d_in[3];
  float* out = (float*)d_out;

  char* ws = (char*)d_ws;
  // layout: Bp 384KB | q 1MB | k 1MB | v 1MB  (~3.4 MB total)
  if (ws_size < 3538944) return;
  bf16_t* Bp = (bf16_t*)ws;
  bf16_t* qw = (bf16_t*)(ws + 393216);
  bf16_t* kw = (bf16_t*)(ws + 393216 + 1048576);
  bf16_t* vw = (bf16_t*)(ws + 393216 + 2097152);

  hipLaunchKernelGGL(wt_kernel, dim3(768), dim3(256), 0, stream, Wq, Wk, Wv, Bp);
  hipLaunchKernelGGL(proj_kernel, dim3(256), dim3(512), 0, stream, tokens, Bp, qw, kw, vw);
  hipLaunchKernelGGL(attn_kernel, dim3(512), dim3(512), 0, stream, qw, kw, vw, out);
}

// Round 9
// 96.040 us; speedup vs baseline: 3.4553x; 1.0553x over previous
//
#include <hip/hip_runtime.h>
#include <stdint.h>

// AttentionHead: B=4, S=2048, E=1024, H=64, causal, scale = E^-0.5 = 1/32.
// R9: consolidation. proj = best-measured R4-source version (512 blk x 256
// thr dbuf, coalesced epilogue). attn = R5 S^T loop + explicit k/v register
// loads with V hoisted above exp2 (latency hidden under softmax VALU).

typedef __bf16 bf16_t;
typedef __bf16 bf16x8 __attribute__((ext_vector_type(8)));
typedef __bf16 bf16x4 __attribute__((ext_vector_type(4)));
typedef float floatx4 __attribute__((ext_vector_type(4)));

#define MFMA16(a, b, c) __builtin_amdgcn_mfma_f32_16x16x32_bf16((a), (b), (c), 0, 0, 0)

// log2(e) / sqrt(1024): folded into Wq so scores come out in exp2 domain.
static constexpr float kQScale = 0.04508422002778f;
#define NEG_BIG (-3.0e38f)

__device__ inline bf16x4 cvt4(float4 f) {
  bf16x4 v;
  v[0] = (bf16_t)f.x; v[1] = (bf16_t)f.y; v[2] = (bf16_t)f.z; v[3] = (bf16_t)f.w;
  return v;
}

// ---------------- kernel 0: W -> Bp in MFMA B-fragment order ---------------
__global__ __launch_bounds__(256) void wt_kernel(const float* __restrict__ Wq,
                                                 const float* __restrict__ Wk,
                                                 const float* __restrict__ Wv,
                                                 bf16_t* __restrict__ Bp) {
  const int tid = blockIdx.x * 256 + threadIdx.x;
  const int j = tid & 7;
  const int lane = (tid >> 3) & 63;
  const int ks = (tid >> 9) & 31;
  const int nt = tid >> 14;
  const int m = nt >> 2, n4 = nt & 3;
  const int h = n4 * 16 + (lane & 15);
  const int e = ks * 32 + ((lane >> 4) << 3) + j;
  const float* W = (m == 0) ? Wq : ((m == 1) ? Wk : Wv);
  float v = W[e * 64 + h];
  if (m == 0) v *= kQScale;
  Bp[tid] = (bf16_t)v;
}

// ---------------- kernel 1: projection GEMM (R4-source, verified) ----------
// grid 512 (16-row M-tiles), block 256 = 4 waves, each wave 3 n-tiles, full K.
// Tokens staged fp32->bf16 through LDS (double-buffered). Epilogue: v stored
// direct (kappa order -> one b64/thread), q/k restaged via LDS -> b128 stores.
__global__ __launch_bounds__(256) void proj_kernel(const float* __restrict__ tok,
                                                   const bf16_t* __restrict__ Bp,
                                                   bf16_t* __restrict__ qw,
                                                   bf16_t* __restrict__ kw,
                                                   bf16_t* __restrict__ vw) {
  __shared__ bf16_t As[2][16][264];
  const int tx = threadIdx.x;
  const int wave = tx >> 6, lane = tx & 63;
  const int lanelo = lane & 15, quad = lane >> 4;
  const int grow = blockIdx.x * 16;
  const int b = grow >> 11;
  const int t = (grow & 2047) >> 4;

  const float* tokbase = tok + (grow + wave) * 1024 + lane * 4;

  floatx4 acc[3];
#pragma unroll
  for (int i = 0; i < 3; i++) acc[i] = (floatx4){0.f, 0.f, 0.f, 0.f};

  const bf16_t* bp[3];
#pragma unroll
  for (int j = 0; j < 3; j++)
    bp[j] = Bp + (wave * 3 + j) * 16384 + lane * 8;

  float4 tb[4];
#pragma unroll
  for (int r = 0; r < 4; r++) tb[r] = *(const float4*)(tokbase + r * 4096);
#pragma unroll
  for (int r = 0; r < 4; r++)
    *(bf16x4*)&As[0][r * 4 + wave][lane * 4] = cvt4(tb[r]);
  __syncthreads();

  for (int c = 0; c < 4; c++) {
    if (c < 3) {
#pragma unroll
      for (int r = 0; r < 4; r++)
        tb[r] = *(const float4*)(tokbase + r * 4096 + (c + 1) * 256);
    }
    const bf16_t* ab = &As[c & 1][lanelo][quad * 8];
#pragma unroll
    for (int ks = 0; ks < 8; ks++) {
      const bf16x8 af = *(const bf16x8*)(ab + ks * 32);
#pragma unroll
      for (int j = 0; j < 3; j++) {
        const bf16x8 bfr = *(const bf16x8*)(bp[j] + (c * 8 + ks) * 512);
        acc[j] = MFMA16(af, bfr, acc[j]);
      }
    }
    if (c < 3) {
#pragma unroll
      for (int r = 0; r < 4; r++)
        *(bf16x4*)&As[(c + 1) & 1][r * 4 + wave][lane * 4] = cvt4(tb[r]);
    }
    __syncthreads();
  }

  bf16_t* Cs = (bf16_t*)As;
#pragma unroll
  for (int j = 0; j < 3; j++) {
    const int nt = wave * 3 + j;
    const int n4 = nt & 3, mtx = nt >> 2;
    if (mtx < 2) {
#pragma unroll
      for (int r = 0; r < 4; r++)
        Cs[(quad * 4 + r) * 136 + mtx * 64 + n4 * 16 + lanelo] = (bf16_t)acc[j][r];
    } else {
      bf16x4 pk;
#pragma unroll
      for (int r = 0; r < 4; r++) pk[r] = (bf16_t)acc[j][r];
      const int base = (((b * 32 + (t >> 2)) * 2 + ((t >> 1) & 1)) * 4 + n4) * 512
                     + (quad * 16 + lanelo) * 8 + (t & 1) * 4;
      *(bf16x4*)(vw + base) = pk;
    }
  }
  __syncthreads();
  {
    const int mtx = tx >> 7, idx = tx & 127;
    const int ds = idx >> 6, lp = idx & 63;
    const int qr = lp & 15, h8 = ds * 32 + ((lp >> 4) << 3);
    const bf16x8 val = *(const bf16x8*)&Cs[qr * 136 + mtx * 64 + h8];
    bf16_t* dst = mtx ? kw : qw;
    *(bf16x8*)(dst + (b * 128 + t) * 1024 + idx * 8) = val;
  }
}

// ---------------- kernel 2: flash attention (S^T loop, V hoisted) ----------
// grid 512 = B * 128 q-tiles of 16 rows (reversed), block 512 = 8 waves, each
// wave takes 64-key chunks c, c+8, ... No LDS/barriers in the loop; k and v
// fragments loaded into explicit registers with V issued BEFORE the exp2
// section so its L2 latency hides under the softmax VALU window.
__global__ __launch_bounds__(512, 4) void attn_kernel(const bf16_t* __restrict__ qw,
                                                      const bf16_t* __restrict__ kw,
                                                      const bf16_t* __restrict__ vw,
                                                      float* __restrict__ out) {
  __shared__ float Ol[8][16][65];
  __shared__ float Ll[8][16];

  const int wave = threadIdx.x >> 6;
  const int lane = threadIdx.x & 63;
  const int lanelo = lane & 15;
  const int quad = lane >> 4;

  const int b = blockIdx.x & 3;
  const int t = 127 - (blockIdx.x >> 2);
  const int qbase = t * 16;
  const int grow = b * 2048 + qbase;

  const bf16_t* qp = qw + ((b * 128 + t) * 128 + lane) * 8;
  const bf16x8 qa0 = *(const bf16x8*)qp;
  const bf16x8 qa1 = *(const bf16x8*)(qp + 512);

  bf16x8 ones;
#pragma unroll
  for (int j = 0; j < 8; j++) ones[j] = (bf16_t)1.0f;

  floatx4 O[4];
#pragma unroll
  for (int i = 0; i < 4; i++) O[i] = (floatx4){0.f, 0.f, 0.f, 0.f};
  floatx4 lacc = (floatx4){0.f, 0.f, 0.f, 0.f};

  const int nch = (qbase + 16 + 63) >> 6;
  const bf16_t* kb = kw + b * 131072 + lane * 8;
  const bf16_t* vb = vw + b * 131072 + lane * 8;

  for (int c = wave; c < nch; c += 8) {
    const int cb = c * 64;
    // ---- k fragments into registers, then S^T = K Q^T ----
    bf16x8 kf[8];
#pragma unroll
    for (int sub = 0; sub < 4; sub++) {
      const bf16_t* kp = kb + (c * 4 + sub) * 1024;
      kf[2 * sub] = *(const bf16x8*)kp;
      kf[2 * sub + 1] = *(const bf16x8*)(kp + 512);
    }
    floatx4 s[4];
    const floatx4 z = (floatx4){0.f, 0.f, 0.f, 0.f};
#pragma unroll
    for (int sub = 0; sub < 4; sub++) {
      s[sub] = MFMA16(kf[2 * sub], qa0, z);
      s[sub] = MFMA16(kf[2 * sub + 1], qa1, s[sub]);
    }

    // ---- V loads issued now: latency hides under mask/exp2 below ----
    const bf16_t* vp = vb + c * 4096;
    bf16x8 vv[8];
#pragma unroll
    for (int dt = 0; dt < 4; dt++) {
      vv[dt] = *(const bf16x8*)(vp + dt * 512);
      vv[4 + dt] = *(const bf16x8*)(vp + 2048 + dt * 512);
    }

    // ---- causal mask ----
    if (cb + 63 > qbase) {
#pragma unroll
      for (int sub = 0; sub < 4; sub++) {
        const int keyr = cb + sub * 16 + quad * 4;
#pragma unroll
        for (int r = 0; r < 4; r++)
          if (keyr + r > qbase + lanelo) s[sub][r] = NEG_BIG;
      }
    }

    // ---- P^T = exp2(S^T); local repack into B-frag (kappa order) ----
    bf16x8 pa0, pa1;
#pragma unroll
    for (int r = 0; r < 4; r++) {
      pa0[r]     = (bf16_t)__builtin_amdgcn_exp2f(s[0][r]);
      pa0[4 + r] = (bf16_t)__builtin_amdgcn_exp2f(s[1][r]);
      pa1[r]     = (bf16_t)__builtin_amdgcn_exp2f(s[2][r]);
      pa1[4 + r] = (bf16_t)__builtin_amdgcn_exp2f(s[3][r]);
    }

    // ---- O^T += V^T P^T ; l += ones . P^T ----
#pragma unroll
    for (int dt = 0; dt < 4; dt++) {
      O[dt] = MFMA16(vv[dt], pa0, O[dt]);
      O[dt] = MFMA16(vv[4 + dt], pa1, O[dt]);
    }
    lacc = MFMA16(ones, pa0, lacc);
    lacc = MFMA16(ones, pa1, lacc);
  }

  // ---- cross-wave merge: plain sums ----
#pragma unroll
  for (int dt = 0; dt < 4; dt++)
#pragma unroll
    for (int r = 0; r < 4; r++)
      Ol[wave][lanelo][dt * 16 + quad * 4 + r] = O[dt][r];
  if (quad == 0) Ll[wave][lanelo] = lacc[0];
  __syncthreads();

#pragma unroll
  for (int o = threadIdx.x; o < 1024; o += 512) {
    const int row = o >> 6, d = o & 63;
    float L = 0.f, acc = 0.f;
#pragma unroll
    for (int w = 0; w < 8; w++) {
      L += Ll[w][row];
      acc += Ol[w][row][d];
    }
    out[(grow + row) * 64 + d] = acc / L;
  }
}

// ---------------- launch ---------------------------------------------------
extern "C" void kernel_launch(void* const* d_in, const int* in_sizes, int n_in,
                              void* d_out, int out_size, void* d_ws, size_t ws_size,
                              hipStream_t stream) {
  const float* tokens = (const float*)d_in[0];
  const float* Wq = (const float*)d_in[1];
  const float* Wk = (const float*)d_in[2];
  const float* Wv = (const float*)d_in[3];
  float* out = (float*)d_out;

  char* ws = (char*)d_ws;
  // layout: Bp 384KB | q 1MB | k 1MB | v 1MB  (~3.4 MB total)
  if (ws_size < 3538944) return;
  bf16_t* Bp = (bf16_t*)ws;
  bf16_t* qw = (bf16_t*)(ws + 393216);
  bf16_t* kw = (bf16_t*)(ws + 393216 + 1048576);
  bf16_t* vw = (bf16_t*)(ws + 393216 + 2097152);

  hipLaunchKernelGGL(wt_kernel, dim3(768), dim3(256), 0, stream, Wq, Wk, Wv, Bp);
  hipLaunchKernelGGL(proj_kernel, dim3(512), dim3(256), 0, stream, tokens, Bp, qw, kw, vw);
  hipLaunchKernelGGL(attn_kernel, dim3(512), dim3(512), 0, stream, qw, kw, vw, out);
}